// Round 1
// baseline (40337.463 us; speedup 1.0000x reference)
//
#include <hip/hip_runtime.h>

// BiRNN: B=128, S=512, E=512, H=1024, V=50000, C=2
// Skewed recurrence: phase p computes h0^(p) (layer0) and h1^(p-1) (layer1)
// for both directions concurrently. 513 phases, 2 kernels/phase.
// All fp32 vector math (correctness baseline; MFMA upgrade later).

#define S_LEN 512
#define NB 128
#define ED 512
#define HD 1024

// ws layout in floats:
#define H0_OFF 0              // [2 dir][2 parity][128][1024] = 524288
#define H1_OFF 524288         // same                         = 524288
#define PART_OFF 1048576      // [2][16 stripes][8 chunks][128][128] = 4194304
#define FC1_OFF 5242880       // [128][64] = 8192
// total 5251072 floats ~= 21 MB

// ---------------------------------------------------------------------------
// Phase GEMM: C(128 x 2048) per direction, where
//   cols [0,1024)    : h0 pre-act = e[t]@Wi0 (K 0..512) + h0@Wh0 (K 512..1536)
//   cols [1024,2048) : h1 pre-act = h0@Wi1 (K 512..1536) + h1@Wh1 (K 1536..2560)
// Grid: 2 dirs x (8 h0-stripes x 6 chunks + 8 h1-stripes x 8 chunks) = 224 blocks.
// Each block: 128 rows x 128 cols, K-chunk of 256, partials to ws.
// ---------------------------------------------------------------------------
__global__ __launch_bounds__(512) void rnn_gemm(
    const int* __restrict__ x, const float* __restrict__ emb,
    const float* __restrict__ f0Wi, const float* __restrict__ f0Wh,
    const float* __restrict__ f1Wi, const float* __restrict__ f1Wh,
    const float* __restrict__ b0Wi, const float* __restrict__ b0Wh,
    const float* __restrict__ b1Wi, const float* __restrict__ b1Wh,
    float* __restrict__ ws, int p)
{
    int bid = blockIdx.x;
    int dir = bid / 112;
    int r   = bid % 112;
    int stripe, chunk;
    if (r < 48) { stripe = r / 6; chunk = r % 6; }
    else        { int r2 = r - 48; stripe = 8 + (r2 >> 3); chunk = r2 & 7; }
    bool isH0 = stripe < 8;
    if (isH0 && p == S_LEN) return;   // no h0 update at final phase
    if (!isH0 && p == 0)    return;   // no h1 update at first phase

    int rp = (p + 1) & 1;  // read parity: buffers written at phase p-1
    const float* h0read = ws + H0_OFF + (size_t)(dir * 2 + rp) * NB * HD;
    const float* h1read = ws + H1_OFF + (size_t)(dir * 2 + rp) * NB * HD;

    const float* Wi0 = dir ? b0Wi : f0Wi;
    const float* Wh0 = dir ? b0Wh : f0Wh;
    const float* Wi1 = dir ? b1Wi : f1Wi;
    const float* Wh1 = dir ? b1Wh : f1Wh;

    int kbase = isH0 ? chunk * 256 : 512 + chunk * 256;
    bool egather = false;
    const float* Aptr = nullptr;
    const float* Wptr;
    int koff, ncol;
    if (isH0) {
        ncol = stripe * 128;
        if (chunk < 2) { egather = true; koff = kbase;
                         Wptr = Wi0 + (size_t)koff * HD + ncol; }
        else           { Aptr = h0read; koff = kbase - 512;
                         Wptr = Wh0 + (size_t)koff * HD + ncol; }
    } else {
        ncol = (stripe - 8) * 128;
        if (chunk < 4) { Aptr = h0read; koff = kbase - 512;
                         Wptr = Wi1 + (size_t)koff * HD + ncol; }
        else           { Aptr = h1read; koff = kbase - 1536;
                         Wptr = Wh1 + (size_t)koff * HD + ncol; }
    }

    __shared__ float As[128][20];    // row stride 80B (16B aligned, padded)
    __shared__ float Wsh[16][132];   // row stride 528B (16B aligned, padded)
    __shared__ int idxs[128];

    int tid = threadIdx.x;
    if (egather && tid < 128) {
        int t = (dir == 0) ? p : (S_LEN - 1 - p);
        idxs[tid] = x[tid * S_LEN + t];
    }
    __syncthreads();

    float acc[4][8];
    #pragma unroll
    for (int i = 0; i < 4; ++i) {
        #pragma unroll
        for (int j = 0; j < 8; ++j) acc[i][j] = 0.f;
    }

    int arow = tid >> 2;           // 0..127
    int aq   = (tid & 3) * 4;      // 0,4,8,12
    int wrow = tid >> 5;           // 0..15
    int wc   = (tid & 31) * 4;     // 0..124
    int ty   = tid >> 4;           // 0..31 -> 4 rows each
    int tx   = tid & 15;           // 8 cols each

    for (int s0 = 0; s0 < 16; ++s0) {
        int k0 = s0 * 16;
        float4 av;
        if (egather) {
            av = *(const float4*)(emb + (size_t)idxs[arow] * ED + (koff + k0 + aq));
        } else {
            av = *(const float4*)(Aptr + (size_t)arow * HD + (koff + k0 + aq));
        }
        float4 wv = *(const float4*)(Wptr + (size_t)(k0 + wrow) * HD + wc);
        *(float4*)&As[arow][aq] = av;
        *(float4*)&Wsh[wrow][wc] = wv;
        __syncthreads();
        #pragma unroll
        for (int kk = 0; kk < 16; ++kk) {
            float b8[8];
            #pragma unroll
            for (int j = 0; j < 8; ++j) b8[j] = Wsh[kk][tx * 8 + j];
            #pragma unroll
            for (int i = 0; i < 4; ++i) {
                float a = As[ty * 4 + i][kk];
                #pragma unroll
                for (int j = 0; j < 8; ++j) acc[i][j] += a * b8[j];
            }
        }
        __syncthreads();
    }

    float* outp = ws + PART_OFF + (size_t)((dir * 16 + stripe) * 8 + chunk) * 16384;
    #pragma unroll
    for (int i = 0; i < 4; ++i) {
        int row = ty * 4 + i;
        #pragma unroll
        for (int j = 0; j < 8; j += 4) {
            float4 v = make_float4(acc[i][j], acc[i][j+1], acc[i][j+2], acc[i][j+3]);
            *(float4*)(outp + row * 128 + tx * 8 + j) = v;
        }
    }
}

// ---------------------------------------------------------------------------
// Reduce partials + biases + tanh -> h buffers (write parity p&1)
// Grid: 2 dirs x 16 stripes = 32 blocks x 256 threads.
// ---------------------------------------------------------------------------
__global__ __launch_bounds__(256) void rnn_reduce(
    const float* __restrict__ f0bi, const float* __restrict__ f0bh,
    const float* __restrict__ f1bi, const float* __restrict__ f1bh,
    const float* __restrict__ b0bi, const float* __restrict__ b0bh,
    const float* __restrict__ b1bi, const float* __restrict__ b1bh,
    float* __restrict__ ws, int p)
{
    int bid = blockIdx.x;
    int dir = bid >> 4, stripe = bid & 15;
    bool isH0 = stripe < 8;
    if (isH0 && p == S_LEN) return;
    if (!isH0 && p == 0)    return;
    int nparts = isH0 ? 6 : 8;
    const float* part = ws + PART_OFF + (size_t)((dir * 16 + stripe) * 8) * 16384;
    int wpar = p & 1;
    float* dst; int ncol;
    const float* bA; const float* bB;
    if (isH0) {
        dst = ws + H0_OFF + (size_t)(dir * 2 + wpar) * NB * HD;
        ncol = stripe * 128;
        bA = dir ? b0bi : f0bi;  bB = dir ? b0bh : f0bh;
    } else {
        dst = ws + H1_OFF + (size_t)(dir * 2 + wpar) * NB * HD;
        ncol = (stripe - 8) * 128;
        bA = dir ? b1bi : f1bi;  bB = dir ? b1bh : f1bh;
    }
    int tid = threadIdx.x;
    for (int e = tid; e < 4096; e += 256) {
        int off = e * 4;
        int row = off >> 7, col = off & 127;
        float4 s = *(const float4*)(part + off);
        for (int q = 1; q < nparts; ++q) {
            float4 v = *(const float4*)(part + (size_t)q * 16384 + off);
            s.x += v.x; s.y += v.y; s.z += v.z; s.w += v.w;
        }
        s.x = tanhf(s.x + bA[ncol + col + 0] + bB[ncol + col + 0]);
        s.y = tanhf(s.y + bA[ncol + col + 1] + bB[ncol + col + 1]);
        s.z = tanhf(s.z + bA[ncol + col + 2] + bB[ncol + col + 2]);
        s.w = tanhf(s.w + bA[ncol + col + 3] + bB[ncol + col + 3]);
        *(float4*)(dst + (size_t)row * HD + ncol + col) = s;
    }
}

// ---------------------------------------------------------------------------
// Epilogue: out = (concat(h_fwd, h_bwd) @ fc1 + b1) @ fc2 + b2
// ---------------------------------------------------------------------------
__global__ __launch_bounds__(64) void fc1_kernel(
    const float* __restrict__ fc1W, const float* __restrict__ fc1b,
    float* __restrict__ ws)
{
    int r = blockIdx.x;      // 0..127
    int c = threadIdx.x;     // 0..63
    const float* hf = ws + H1_OFF + (size_t)r * HD;                      // dir0 par0
    const float* hb = ws + H1_OFF + (size_t)2 * NB * HD + (size_t)r * HD; // dir1 par0
    float s = fc1b[c];
    for (int k = 0; k < HD; ++k) s += hf[k] * fc1W[k * 64 + c];
    for (int k = 0; k < HD; ++k) s += hb[k] * fc1W[(HD + k) * 64 + c];
    ws[FC1_OFF + r * 64 + c] = s;
}

__global__ __launch_bounds__(256) void fc2_kernel(
    const float* __restrict__ fc2W, const float* __restrict__ fc2b,
    const float* __restrict__ ws, float* __restrict__ out)
{
    int tid = threadIdx.x;   // 256 = 128 rows x 2 cols
    int r = tid >> 1, c = tid & 1;
    const float* f = ws + FC1_OFF + r * 64;
    float s = fc2b[c];
    for (int k = 0; k < 64; ++k) s += f[k] * fc2W[k * 2 + c];
    out[r * 2 + c] = s;
}

extern "C" void kernel_launch(void* const* d_in, const int* in_sizes, int n_in,
                              void* d_out, int out_size, void* d_ws, size_t ws_size,
                              hipStream_t stream)
{
    const int*   x    = (const int*)d_in[0];
    const float* emb  = (const float*)d_in[1];
    const float* f0Wi = (const float*)d_in[2];
    const float* f0bi = (const float*)d_in[3];
    const float* f0Wh = (const float*)d_in[4];
    const float* f0bh = (const float*)d_in[5];
    const float* f1Wi = (const float*)d_in[6];
    const float* f1bi = (const float*)d_in[7];
    const float* f1Wh = (const float*)d_in[8];
    const float* f1bh = (const float*)d_in[9];
    const float* b0Wi = (const float*)d_in[10];
    const float* b0bi = (const float*)d_in[11];
    const float* b0Wh = (const float*)d_in[12];
    const float* b0bh = (const float*)d_in[13];
    const float* b1Wi = (const float*)d_in[14];
    const float* b1bi = (const float*)d_in[15];
    const float* b1Wh = (const float*)d_in[16];
    const float* b1bh = (const float*)d_in[17];
    const float* fc1W = (const float*)d_in[18];
    const float* fc1b = (const float*)d_in[19];
    const float* fc2W = (const float*)d_in[20];
    const float* fc2b = (const float*)d_in[21];
    float* ws  = (float*)d_ws;
    float* out = (float*)d_out;

    // zero h state (both parities, both layers, both dirs): 4 MB
    hipMemsetAsync(d_ws, 0, (size_t)1048576 * 4, stream);

    for (int p = 0; p <= S_LEN; ++p) {
        rnn_gemm<<<224, 512, 0, stream>>>(x, emb, f0Wi, f0Wh, f1Wi, f1Wh,
                                          b0Wi, b0Wh, b1Wi, b1Wh, ws, p);
        rnn_reduce<<<32, 256, 0, stream>>>(f0bi, f0bh, f1bi, f1bh,
                                           b0bi, b0bh, b1bi, b1bh, ws, p);
    }
    fc1_kernel<<<128, 64, 0, stream>>>(fc1W, fc1b, ws);
    fc2_kernel<<<1, 256, 0, stream>>>(fc2W, fc2b, ws, out);
}

// Round 2
// 18716.531 us; speedup vs baseline: 2.1552x; 2.1552x over previous
//
#include <hip/hip_runtime.h>

// BiRNN: B=128, S=512, E=512, H=1024, V=50000, C=2
// Skewed recurrence, phase p: h0^(p) and h1^(p-1), both dirs.
// GEMM via bf16x3 split-precision MFMA (hi/lo decomposition, fp32 accum).

#define S_LEN 512

typedef short bf16x8 __attribute__((ext_vector_type(8)));
typedef float f32x4 __attribute__((ext_vector_type(4)));

__device__ __forceinline__ unsigned short f2bf(float f) {
    unsigned u = __float_as_uint(f);
    u += 0x7fff + ((u >> 16) & 1);
    return (unsigned short)(u >> 16);
}
__device__ __forceinline__ float bf2f(unsigned short h) {
    return __uint_as_float(((unsigned)h) << 16);
}
__device__ __forceinline__ f32x4 mfma16(bf16x8 a, bf16x8 b, f32x4 c) {
    return __builtin_amdgcn_mfma_f32_16x16x32_bf16(a, b, c, 0, 0, 0);
}

// ws layout (bytes):
//  WT_hi  [2 dir][3670016]         @ 0          (14,680,064)
//  WT_lo                            @ 14680064   (14,680,064)
//  H_hi   [2 layer][2 dir][2 par][128*1024] @ 29360128 (2,097,152)
//  H_lo                             @ 31457280   (2,097,152)
//  E_hi   [2 dir][2 par][128*512]   @ 33554432   (524,288)
//  E_lo                             @ 34078720   (524,288)
//  PART   [2][16][8][128*128] f32   @ 34603008   (16,777,216)
//  FC1    [128][64] f32             @ 51380224   (32,768)
// per-dir WT mat offsets (elems): Wi0T 0 (K=512), Wh0T 524288, Wi1T 1572864, Wh1T 2621440

// ---------------------------------------------------------------------------
// One-time weight conversion: W[K][1024] fp32 -> WT_hi/lo [1024][K] bf16
// ---------------------------------------------------------------------------
__global__ __launch_bounds__(256) void conv_weight(
    const float* __restrict__ W, unsigned short* __restrict__ dhi,
    unsigned short* __restrict__ dlo, int K)
{
    int t = blockIdx.x * 256 + threadIdx.x;
    int n = t & 1023;
    int k0 = (t >> 10) << 3;
    if (k0 >= K) return;
    unsigned short hh[8], ll[8];
    #pragma unroll
    for (int j = 0; j < 8; ++j) {
        float w = W[(size_t)(k0 + j) * 1024 + n];
        unsigned short h = f2bf(w);
        hh[j] = h;
        ll[j] = f2bf(w - bf2f(h));
    }
    size_t o = (size_t)n * K + k0;
    *(ushort4*)(dhi + o)     = make_ushort4(hh[0], hh[1], hh[2], hh[3]);
    *(ushort4*)(dhi + o + 4) = make_ushort4(hh[4], hh[5], hh[6], hh[7]);
    *(ushort4*)(dlo + o)     = make_ushort4(ll[0], ll[1], ll[2], ll[3]);
    *(ushort4*)(dlo + o + 4) = make_ushort4(ll[4], ll[5], ll[6], ll[7]);
}

// ---------------------------------------------------------------------------
// Embedding gather + hi/lo split for phase pc (double-buffered by pc&1)
// eb in 0..7: dir = eb>>2, rowgroup = eb&3 (32 rows each)
// ---------------------------------------------------------------------------
__device__ __forceinline__ void prep_e(int eb, int tid, const int* __restrict__ x,
    const float* __restrict__ emb, unsigned short* __restrict__ Ehi,
    unsigned short* __restrict__ Elo, int pc)
{
    if (pc > 511) return;
    int dir = eb >> 2, rg = eb & 3;
    int tsel = dir ? (511 - pc) : pc;
    int pe = pc & 1;
    unsigned short* ehi = Ehi + (size_t)(dir * 2 + pe) * 65536;
    unsigned short* elo = Elo + (size_t)(dir * 2 + pe) * 65536;
    for (int i = 0; i < 16; ++i) {
        int q = i * 256 + tid;          // 0..4095
        int rowl = q >> 7;              // 0..31
        int c4 = (q & 127) * 4;
        int m = rg * 32 + rowl;
        int idx = x[m * S_LEN + tsel];
        float4 v = *(const float4*)(emb + (size_t)idx * 512 + c4);
        ushort4 h4, l4;
        h4.x = f2bf(v.x); l4.x = f2bf(v.x - bf2f(h4.x));
        h4.y = f2bf(v.y); l4.y = f2bf(v.y - bf2f(h4.y));
        h4.z = f2bf(v.z); l4.z = f2bf(v.z - bf2f(h4.z));
        h4.w = f2bf(v.w); l4.w = f2bf(v.w - bf2f(h4.w));
        *(ushort4*)(ehi + (size_t)m * 512 + c4) = h4;
        *(ushort4*)(elo + (size_t)m * 512 + c4) = l4;
    }
}

__global__ __launch_bounds__(256) void prep_e_kernel(const int* __restrict__ x,
    const float* __restrict__ emb, unsigned short* __restrict__ Ehi,
    unsigned short* __restrict__ Elo, int pc)
{
    prep_e(blockIdx.x, threadIdx.x, x, emb, Ehi, Elo, pc);
}

// ---------------------------------------------------------------------------
// Phase GEMM (MFMA bf16x3). 224 blocks x 512 thr. Block: 128x128 out tile,
// K-chunk 256. Partials fp32 to ws.
// ---------------------------------------------------------------------------
__global__ __launch_bounds__(512) void rnn_gemm(
    const unsigned short* __restrict__ WThi, const unsigned short* __restrict__ WTlo,
    const unsigned short* __restrict__ Hhi, const unsigned short* __restrict__ Hlo,
    const unsigned short* __restrict__ Ehi, const unsigned short* __restrict__ Elo,
    float* __restrict__ part, int p)
{
    int bid = blockIdx.x;
    int dir = bid / 112;
    int r = bid % 112;
    int stripe, chunk;
    if (r < 48) { stripe = r / 6; chunk = r % 6; }
    else        { int r2 = r - 48; stripe = 8 + (r2 >> 3); chunk = r2 & 7; }
    bool isH0 = stripe < 8;
    if (isH0 && p == S_LEN) return;
    if (!isH0 && p == 0)    return;
    int rp = (p + 1) & 1;

    int matoff, Kmat, koff, hsel = 0;
    bool egather = false;
    if (isH0) {
        if (chunk < 2) { egather = true; matoff = 0; Kmat = 512; koff = chunk * 256; }
        else           { matoff = 524288;  Kmat = 1024; koff = chunk * 256 - 512;  hsel = 0; }
    } else {
        if (chunk < 4) { matoff = 1572864; Kmat = 1024; koff = chunk * 256;        hsel = 0; }
        else           { matoff = 2621440; Kmat = 1024; koff = chunk * 256 - 1024; hsel = 1; }
    }
    const unsigned short* wbhi = WThi + (size_t)dir * 3670016 + matoff;
    const unsigned short* wblo = WTlo + (size_t)dir * 3670016 + matoff;
    const unsigned short* abhi;
    const unsigned short* ablo;
    int astride;
    if (egather) {
        abhi = Ehi + (size_t)(dir * 2 + (p & 1)) * 65536;
        ablo = Elo + (size_t)(dir * 2 + (p & 1)) * 65536;
        astride = 512;
    } else {
        abhi = Hhi + (size_t)((hsel * 2 + dir) * 2 + rp) * 131072;
        ablo = Hlo + (size_t)((hsel * 2 + dir) * 2 + rp) * 131072;
        astride = 1024;
    }

    int tid = threadIdx.x;
    int lane = tid & 63, wid = tid >> 6;
    int wm = (wid >> 2) * 64;       // wave row base (0/64)
    int wn = (wid & 3) * 32;        // wave col base (0/32/64/96)
    int lrow = lane & 15;
    int kgrp = lane >> 4;
    int cstart = (stripe & 7) * 128;

    int arow[4], ncol[2];
    #pragma unroll
    for (int i = 0; i < 4; ++i) arow[i] = wm + i * 16 + lrow;
    #pragma unroll
    for (int j = 0; j < 2; ++j) ncol[j] = cstart + wn + j * 16 + lrow;

    f32x4 acc[4][2];
    #pragma unroll
    for (int i = 0; i < 4; ++i)
        #pragma unroll
        for (int j = 0; j < 2; ++j) acc[i][j] = (f32x4){0.f, 0.f, 0.f, 0.f};

    #pragma unroll 2
    for (int s = 0; s < 8; ++s) {
        int kk = koff + s * 32 + kgrp * 8;
        bf16x8 ahi[4], alo[4], bhi[2], blo[2];
        #pragma unroll
        for (int i = 0; i < 4; ++i) {
            size_t ao = (size_t)arow[i] * astride + kk;
            ahi[i] = *(const bf16x8*)(abhi + ao);
            alo[i] = *(const bf16x8*)(ablo + ao);
        }
        #pragma unroll
        for (int j = 0; j < 2; ++j) {
            size_t bo = (size_t)ncol[j] * Kmat + kk;
            bhi[j] = *(const bf16x8*)(wbhi + bo);
            blo[j] = *(const bf16x8*)(wblo + bo);
        }
        #pragma unroll
        for (int i = 0; i < 4; ++i)
            #pragma unroll
            for (int j = 0; j < 2; ++j) {
                acc[i][j] = mfma16(ahi[i], bhi[j], acc[i][j]);
                acc[i][j] = mfma16(ahi[i], blo[j], acc[i][j]);
                acc[i][j] = mfma16(alo[i], bhi[j], acc[i][j]);
            }
    }

    float* outp = part + (size_t)((dir * 16 + stripe) * 8 + chunk) * 16384;
    #pragma unroll
    for (int i = 0; i < 4; ++i)
        #pragma unroll
        for (int j = 0; j < 2; ++j) {
            int col = wn + j * 16 + lrow;
            #pragma unroll
            for (int r4 = 0; r4 < 4; ++r4) {
                int row = wm + i * 16 + kgrp * 4 + r4;
                outp[row * 128 + col] = acc[i][j][r4];
            }
        }
}

// ---------------------------------------------------------------------------
// Reduce partials + bias + tanh -> H hi/lo (parity p&1). Blocks 128..135
// prepare next phase's embedding operand.
// ---------------------------------------------------------------------------
__global__ __launch_bounds__(256) void rnn_reduce(
    const float* __restrict__ f0bi, const float* __restrict__ f0bh,
    const float* __restrict__ f1bi, const float* __restrict__ f1bh,
    const float* __restrict__ b0bi, const float* __restrict__ b0bh,
    const float* __restrict__ b1bi, const float* __restrict__ b1bh,
    const int* __restrict__ x, const float* __restrict__ emb,
    const float* __restrict__ part,
    unsigned short* __restrict__ Hhi, unsigned short* __restrict__ Hlo,
    unsigned short* __restrict__ Ehi, unsigned short* __restrict__ Elo, int p)
{
    int bid = blockIdx.x, tid = threadIdx.x;
    if (bid >= 128) { prep_e(bid - 128, tid, x, emb, Ehi, Elo, p + 1); return; }
    int dir = bid >> 6, rem = bid & 63;
    int stripe = rem >> 2, rg = rem & 3;
    bool isH0 = stripe < 8;
    if (isH0 && p == S_LEN) return;
    if (!isH0 && p == 0)    return;
    int nparts = isH0 ? 6 : 8;
    const float* pb = part + (size_t)((dir * 16 + stripe) * 8) * 16384;
    int wpar = p & 1;
    int hsel = isH0 ? 0 : 1;
    unsigned short* dsthi = Hhi + (size_t)((hsel * 2 + dir) * 2 + wpar) * 131072;
    unsigned short* dstlo = Hlo + (size_t)((hsel * 2 + dir) * 2 + wpar) * 131072;
    const float *bA, *bB;
    if (isH0) { bA = dir ? b0bi : f0bi; bB = dir ? b0bh : f0bh; }
    else      { bA = dir ? b1bi : f1bi; bB = dir ? b1bh : f1bh; }
    int cstart = (stripe & 7) * 128;

    for (int i = 0; i < 4; ++i) {
        int q = i * 256 + tid;          // 0..1023
        int rowl = q >> 5, c4 = (q & 31) * 4;
        int row = rg * 32 + rowl;
        int off = row * 128 + c4;
        float4 s = *(const float4*)(pb + off);
        for (int u = 1; u < nparts; ++u) {
            float4 v = *(const float4*)(pb + (size_t)u * 16384 + off);
            s.x += v.x; s.y += v.y; s.z += v.z; s.w += v.w;
        }
        int gc = cstart + c4;
        s.x = tanhf(s.x + bA[gc]     + bB[gc]);
        s.y = tanhf(s.y + bA[gc + 1] + bB[gc + 1]);
        s.z = tanhf(s.z + bA[gc + 2] + bB[gc + 2]);
        s.w = tanhf(s.w + bA[gc + 3] + bB[gc + 3]);
        ushort4 h4, l4;
        h4.x = f2bf(s.x); l4.x = f2bf(s.x - bf2f(h4.x));
        h4.y = f2bf(s.y); l4.y = f2bf(s.y - bf2f(h4.y));
        h4.z = f2bf(s.z); l4.z = f2bf(s.z - bf2f(h4.z));
        h4.w = f2bf(s.w); l4.w = f2bf(s.w - bf2f(h4.w));
        *(ushort4*)(dsthi + (size_t)row * 1024 + gc) = h4;
        *(ushort4*)(dstlo + (size_t)row * 1024 + gc) = l4;
    }
}

// ---------------------------------------------------------------------------
// Epilogue
// ---------------------------------------------------------------------------
__global__ __launch_bounds__(64) void fc1_kernel(
    const float* __restrict__ fc1W, const float* __restrict__ fc1b,
    const unsigned short* __restrict__ Hhi, const unsigned short* __restrict__ Hlo,
    float* __restrict__ fc1out)
{
    int r = blockIdx.x;      // 0..127
    int c = threadIdx.x;     // 0..63
    const unsigned short* fh = Hhi + (size_t)4 * 131072 + r * 1024; // layer1 dir0 par0
    const unsigned short* fl = Hlo + (size_t)4 * 131072 + r * 1024;
    const unsigned short* bh = Hhi + (size_t)6 * 131072 + r * 1024; // layer1 dir1 par0
    const unsigned short* bl = Hlo + (size_t)6 * 131072 + r * 1024;
    float s = fc1b[c];
    for (int k = 0; k < 1024; ++k)
        s += (bf2f(fh[k]) + bf2f(fl[k])) * fc1W[k * 64 + c];
    for (int k = 0; k < 1024; ++k)
        s += (bf2f(bh[k]) + bf2f(bl[k])) * fc1W[(1024 + k) * 64 + c];
    fc1out[r * 64 + c] = s;
}

__global__ __launch_bounds__(256) void fc2_kernel(
    const float* __restrict__ fc2W, const float* __restrict__ fc2b,
    const float* __restrict__ fc1out, float* __restrict__ out)
{
    int tid = threadIdx.x;   // 128 rows x 2 cols
    int r = tid >> 1, c = tid & 1;
    const float* f = fc1out + r * 64;
    float s = fc2b[c];
    for (int k = 0; k < 64; ++k) s += f[k] * fc2W[k * 2 + c];
    out[r * 2 + c] = s;
}

extern "C" void kernel_launch(void* const* d_in, const int* in_sizes, int n_in,
                              void* d_out, int out_size, void* d_ws, size_t ws_size,
                              hipStream_t stream)
{
    const int*   x    = (const int*)d_in[0];
    const float* emb  = (const float*)d_in[1];
    const float* f0Wi = (const float*)d_in[2];
    const float* f0bi = (const float*)d_in[3];
    const float* f0Wh = (const float*)d_in[4];
    const float* f0bh = (const float*)d_in[5];
    const float* f1Wi = (const float*)d_in[6];
    const float* f1bi = (const float*)d_in[7];
    const float* f1Wh = (const float*)d_in[8];
    const float* f1bh = (const float*)d_in[9];
    const float* b0Wi = (const float*)d_in[10];
    const float* b0bi = (const float*)d_in[11];
    const float* b0Wh = (const float*)d_in[12];
    const float* b0bh = (const float*)d_in[13];
    const float* b1Wi = (const float*)d_in[14];
    const float* b1bi = (const float*)d_in[15];
    const float* b1Wh = (const float*)d_in[16];
    const float* b1bh = (const float*)d_in[17];
    const float* fc1W = (const float*)d_in[18];
    const float* fc1b = (const float*)d_in[19];
    const float* fc2W = (const float*)d_in[20];
    const float* fc2b = (const float*)d_in[21];
    float* out = (float*)d_out;

    char* wsb = (char*)d_ws;
    unsigned short* WThi = (unsigned short*)(wsb);
    unsigned short* WTlo = (unsigned short*)(wsb + 14680064);
    unsigned short* Hhi  = (unsigned short*)(wsb + 29360128);
    unsigned short* Hlo  = (unsigned short*)(wsb + 31457280);
    unsigned short* Ehi  = (unsigned short*)(wsb + 33554432);
    unsigned short* Elo  = (unsigned short*)(wsb + 34078720);
    float* part   = (float*)(wsb + 34603008);
    float* fc1out = (float*)(wsb + 51380224);

    // one-time weight conversion (8 matrices)
    conv_weight<<<256, 256, 0, stream>>>(f0Wi, WThi + 0,       WTlo + 0,       512);
    conv_weight<<<512, 256, 0, stream>>>(f0Wh, WThi + 524288,  WTlo + 524288,  1024);
    conv_weight<<<512, 256, 0, stream>>>(f1Wi, WThi + 1572864, WTlo + 1572864, 1024);
    conv_weight<<<512, 256, 0, stream>>>(f1Wh, WThi + 2621440, WTlo + 2621440, 1024);
    conv_weight<<<256, 256, 0, stream>>>(b0Wi, WThi + 3670016 + 0,       WTlo + 3670016 + 0,       512);
    conv_weight<<<512, 256, 0, stream>>>(b0Wh, WThi + 3670016 + 524288,  WTlo + 3670016 + 524288,  1024);
    conv_weight<<<512, 256, 0, stream>>>(b1Wi, WThi + 3670016 + 1572864, WTlo + 3670016 + 1572864, 1024);
    conv_weight<<<512, 256, 0, stream>>>(b1Wh, WThi + 3670016 + 2621440, WTlo + 3670016 + 2621440, 1024);

    // zero h state (hi+lo, all layers/dirs/parities)
    hipMemsetAsync(wsb + 29360128, 0, 4194304, stream);
    // initial embedding operand for phase 0
    prep_e_kernel<<<8, 256, 0, stream>>>(x, emb, Ehi, Elo, 0);

    for (int p = 0; p <= S_LEN; ++p) {
        rnn_gemm<<<224, 512, 0, stream>>>(WThi, WTlo, Hhi, Hlo, Ehi, Elo, part, p);
        rnn_reduce<<<136, 256, 0, stream>>>(f0bi, f0bh, f1bi, f1bh,
                                            b0bi, b0bh, b1bi, b1bh,
                                            x, emb, part, Hhi, Hlo, Ehi, Elo, p);
    }
    fc1_kernel<<<128, 64, 0, stream>>>(fc1W, fc1b, Hhi, Hlo, fc1out);
    fc2_kernel<<<1, 256, 0, stream>>>(fc2W, fc2b, fc1out, out);
}